// Round 10
// baseline (24714.302 us; speedup 1.0000x reference)
//
#include <hip/hip_runtime.h>
#include <stdint.h>

#define BB 128
#define TT 512
#define EE 128
#define HH 256
#define KK 32

// Workspace: hring f32 [2par][2dir][B][H] @0 (512 KB)
//            cring f32 [2par][2dir][B][H] @512K (512 KB)
//            em    f64 [B][T][K]          @2M (16 MB)
#define OFF_CR (512ull << 10)
#define OFF_EM (2ull << 20)

// ---------------------------------------------------------------------------
// k_step: one BiLSTM step, both dirs (launched 512x).  F32-LATTICE pipeline:
// mimics the reference's float32 rounding points exactly —
//   xg   = f32(sum_x) + b              (per-element f32 add)
//   g    = xg + f32(sum_h)             (f32 add)
//   gates: sigmoid/tanh in f32;  c,h stored f32 (fed back each step)
// Dot products accumulate in f64 and round ONCE to f32 (deviation from np's
// own f32-blocked sums ~1e-7 — the noise class that flips no tags).
// Grid 256 = 2dir x 8 batch-tiles(16) x 16 hidden-slices(16). LDS ~28 KB.
// ---------------------------------------------------------------------------
__global__ __launch_bounds__(256) void k_step(int s,
        const int* __restrict__ tok, const float* __restrict__ table,
        const float* __restrict__ Wihf, const float* __restrict__ Whhf,
        const float* __restrict__ bf,
        const float* __restrict__ Wihb, const float* __restrict__ Whhb,
        const float* __restrict__ bb,
        const float* __restrict__ lw,
        float* __restrict__ hring, float* __restrict__ cring,
        double* __restrict__ em) {
    __shared__ float Ax[16 * 128];        // x_t tile
    __shared__ float Ah[16 * 256];        // h_{t-1} tile (f32 lattice)
    __shared__ float Gl[16 * 64];         // f32 gate values
    __shared__ int   tokS[16];

    const int tid  = threadIdx.x;
    const int blk  = blockIdx.x;
    const int dir  = blk >> 7;
    const int tile = (blk >> 4) & 7;
    const int hsl  = blk & 15;
    const int b0   = tile * 16;
    const int u0   = hsl * 16;

    const int t  = dir ? (TT - 1 - s) : s;
    const int wp = s & 1;
    const int rp = wp ^ 1;

    const float* Wih = dir ? Wihb : Wihf;
    const float* Whh = dir ? Whhb : Whhf;
    const float* bia = dir ? bb : bf;

    // ---- emissions partial for step s-1 (h of previous launch, f32) ----
    if (s >= 1) {
        const int d    = blk * 32 + (tid >> 3);   // 0..8191
        const int sub  = tid & 7;
        const int dirm = d >> 12;
        const int rem  = d & 4095;
        const int b    = rem >> 5;
        const int k    = rem & 31;
        const int t_em = dirm ? (TT - s) : (s - 1);
        const float* hrow = hring + ((size_t)((rp * 2 + dirm) * BB + b)) * HH;
        const float* wrow = lw + (size_t)k * (2 * HH) + dirm * HH;
        double p = 0.0;
#pragma unroll
        for (int j = sub * 32; j < sub * 32 + 32; ++j)
            p += (double)hrow[j] * (double)wrow[j];
        p += __shfl_xor(p, 1, 64);
        p += __shfl_xor(p, 2, 64);
        p += __shfl_xor(p, 4, 64);
        if (sub == 0) {
            const size_t idx = ((size_t)b * TT + t_em) * KK + k;
            em[idx] = em[idx] + p;        // exclusive writer per idx per launch
        }
    }

    // ---- stage tokens, x_t, h_{t-1} ----
    if (tid < 16) tokS[tid] = tok[(b0 + tid) * TT + t];
    __syncthreads();
    {
        int i = tid;
#pragma unroll
        for (int rep = 0; rep < 2; ++rep, i += 256) {   // 512 float4 of x
            int r = i >> 5, e4 = i & 31;
            int tk = tokS[r];
            float4 v = make_float4(0.f, 0.f, 0.f, 0.f);
            if (tk != 0) v = ((const float4*)(table + (size_t)tk * EE))[e4];
            *((float4*)(Ax + r * 128 + e4 * 4)) = v;
        }
    }
    if (s == 0) {
        for (int i = tid; i < 1024; i += 256) {         // 1024 float4 zeros
            int r = i >> 6, q = i & 63;
            *((float4*)(Ah + r * 256 + q * 4)) = make_float4(0, 0, 0, 0);
        }
    } else {
        int i = tid;
#pragma unroll
        for (int rep = 0; rep < 4; ++rep, i += 256) {   // 1024 float4 of h
            int r = i >> 6, q = i & 63;
            float4 v = ((const float4*)(hring +
                    ((size_t)((rp * 2 + dir) * BB + b0 + r)) * HH))[q];
            *((float4*)(Ah + r * 256 + q * 4)) = v;
        }
    }
    __syncthreads();

    // ---- gate GEMM: lane c = gate-col (64), wave w = rows 4w..4w+3 ----
    {
        const int c = tid & 63;
        const int w = tid >> 6;
        const int g = c >> 4, uu = c & 15;
        const float bia_c = bia[g * HH + u0 + uu];
        const float* Wr_ih = Wih + (size_t)(g * HH + u0 + uu) * EE;
        const float* Wr_hh = Whh + (size_t)(g * HH + u0 + uu) * HH;
#pragma unroll
        for (int m = 0; m < 4; ++m) {
            const float* X = Ax + (4 * w + m) * 128;
            const float* H = Ah + (4 * w + m) * 256;
            double ax = 0.0;
#pragma unroll 8
            for (int k = 0; k < EE; k += 4) {
                float4 wv = *((const float4*)(Wr_ih + k));
                float4 xv = *((const float4*)(X + k));
                ax += (double)xv.x * wv.x + (double)xv.y * wv.y +
                      (double)xv.z * wv.z + (double)xv.w * wv.w;
            }
            double ah = 0.0;
#pragma unroll 8
            for (int k = 0; k < HH; k += 4) {
                float4 wv = *((const float4*)(Wr_hh + k));
                float4 hv = *((const float4*)(H + k));
                ah += (double)hv.x * wv.x + (double)hv.y * wv.y +
                      (double)hv.z * wv.z + (double)hv.w * wv.w;
            }
            // reference f32 rounding points:
            const float xg = __fadd_rn((float)ax, bia_c);   // f32(Σx)+b
            const float gv = __fadd_rn(xg, (float)ah);      // xg + f32(Σh)
            Gl[(4 * w + m) * 64 + c] = gv;
        }
    }
    __syncthreads();

    // ---- LSTM cell (f32, matching reference elementwise ops) ----
    {
        const int er = tid >> 4, eu = tid & 15;
        const float gi = Gl[er * 64 +  0 + eu];
        const float gf = Gl[er * 64 + 16 + eu];
        const float gg = Gl[er * 64 + 32 + eu];
        const float go = Gl[er * 64 + 48 + eu];
        const float si = 1.f / (1.f + expf(-gi));
        const float sf = 1.f / (1.f + expf(-gf));
        const float so = 1.f / (1.f + expf(-go));
        const float tg = tanhf(gg);
        const size_t widx = ((size_t)((wp * 2 + dir) * BB + b0 + er)) * HH + u0 + eu;
        const size_t ridx = ((size_t)((rp * 2 + dir) * BB + b0 + er)) * HH + u0 + eu;
        const float cprev = (s == 0) ? 0.f : cring[ridx];
        const float c1 = __fmul_rn(sf, cprev);
        const float c2 = __fmul_rn(si, tg);
        const float cnew = __fadd_rn(c1, c2);
        cring[widx] = cnew;
        hring[widx] = __fmul_rn(so, tanhf(cnew));
    }
}

// ---------------------------------------------------------------------------
// k_emlast: emissions for the final launch (wp=1 slots): dir0->t=511,
// dir1->t=0.  8192 dots, one thread each.
// ---------------------------------------------------------------------------
__global__ __launch_bounds__(256) void k_emlast(const float* __restrict__ hring,
                                                const float* __restrict__ lw,
                                                double* __restrict__ em) {
    const int d = blockIdx.x * 256 + threadIdx.x;   // 0..8191
    const int dirm = d >> 12;
    const int rem  = d & 4095;
    const int b    = rem >> 5;
    const int k    = rem & 31;
    const int t_em = dirm ? 0 : (TT - 1);
    const float* hrow = hring + ((size_t)((1 * 2 + dirm) * BB + b)) * HH;
    const float* wrow = lw + (size_t)k * (2 * HH) + dirm * HH;
    double p = 0.0;
#pragma unroll 8
    for (int j = 0; j < HH; ++j)
        p += (double)hrow[j] * (double)wrow[j];
    const size_t idx = ((size_t)b * TT + t_em) * KK + k;
    em[idx] = em[idx] + p;
}

// ---------------------------------------------------------------------------
// k_viterbi: FLOAT32 DP matching the reference's rounding and order:
//   em_lb = f32(em) + lb;  score0 = start + em_lb[0]
//   cand  = f32(f32(score_i + trans_ij) + em_lb[t,j]);  first-max argmax
//   final: score += end;  first-max argmax;  exact backtrace.
// One wave per sequence; lane j = state (duplicated across halves), halves
// split the i-loop; cross-half merge keeps lower i on exact ties.
// ---------------------------------------------------------------------------
__global__ __launch_bounds__(64) void k_viterbi(const double* __restrict__ em,
                                                const float* __restrict__ lb,
                                                const float* __restrict__ startt,
                                                const float* __restrict__ endt,
                                                const float* __restrict__ trans,
                                                int* __restrict__ out) {
    const int b = blockIdx.x;
    const int lane = threadIdx.x;
    const int j = lane & 31, half = lane >> 5;
    __shared__ float trs[32][33];
    __shared__ unsigned char hist[TT][32];
    __shared__ int tags[TT];

    for (int idx = lane; idx < 1024; idx += 64)
        trs[idx >> 5][idx & 31] = trans[idx];
    __syncthreads();

    const float lbj = lb[j];
    const double* emb = em + (size_t)b * TT * KK;
    float score = __fadd_rn(startt[j], __fadd_rn((float)emb[j], lbj));

    for (int t = 1; t < TT; ++t) {
        const float e_cur = __fadd_rn((float)emb[(size_t)t * KK + j], lbj);
        float best = -3.4e38f; int bi = 0;
#pragma unroll
        for (int ii = 0; ii < 16; ++ii) {
            int i = half * 16 + ii;
            float sc_i = __shfl(score, i, 64);
            float c1 = __fadd_rn(sc_i, trs[i][j]);
            float cand = __fadd_rn(c1, e_cur);
            if (cand > best) { best = cand; bi = i; }   // strict > = first max
        }
        float ob = __shfl_xor(best, 32, 64);
        int obi = __shfl_xor(bi, 32, 64);
        if (ob > best || (ob == best && obi < bi)) { best = ob; bi = obi; }
        score = best;
        if (half == 0) hist[t][j] = (unsigned char)bi;
    }

    score = __fadd_rn(score, endt[j]);
    int bj = j; float bs = score;
#pragma unroll
    for (int off = 16; off >= 1; off >>= 1) {
        float os = __shfl_xor(bs, off, 64);
        int oj = __shfl_xor(bj, off, 64);
        if (os > bs || (os == bs && oj < bj)) { bs = os; bj = oj; }
    }
    __syncthreads();
    if (lane == 0) {
        int cur = bj;
        tags[TT - 1] = cur;
        for (int t = TT - 2; t >= 0; --t) { cur = hist[t + 1][cur]; tags[t] = cur; }
    }
    __syncthreads();
    for (int t2 = lane; t2 < TT; t2 += 64) out[b * TT + t2] = tags[t2];
}

// ---------------------------------------------------------------------------
extern "C" void kernel_launch(void* const* d_in, const int* in_sizes, int n_in,
                              void* d_out, int out_size, void* d_ws, size_t ws_size,
                              hipStream_t stream) {
    const int*   tok   = (const int*)d_in[0];
    const float* table = (const float*)d_in[3];
    const float* Wihf  = (const float*)d_in[4];
    const float* Whhf  = (const float*)d_in[5];
    const float* bf    = (const float*)d_in[6];
    const float* Wihb  = (const float*)d_in[7];
    const float* Whhb  = (const float*)d_in[8];
    const float* bb    = (const float*)d_in[9];
    const float* lw    = (const float*)d_in[10];
    const float* lb    = (const float*)d_in[11];
    const float* st    = (const float*)d_in[12];
    const float* en    = (const float*)d_in[13];
    const float* tr    = (const float*)d_in[14];

    if (ws_size < (18ull << 20)) return;

    char* ws = (char*)d_ws;
    float*  hring = (float*)ws;
    float*  cring = (float*)(ws + OFF_CR);
    double* em    = (double*)(ws + OFF_EM);

    hipMemsetAsync(em, 0, (size_t)BB * TT * KK * 8, stream);
    for (int s = 0; s < TT; ++s)
        k_step<<<256, 256, 0, stream>>>(s, tok, table, Wihf, Whhf, bf,
                                        Wihb, Whhb, bb, lw, hring, cring, em);
    k_emlast<<<32, 256, 0, stream>>>(hring, lw, em);
    k_viterbi<<<BB, 64, 0, stream>>>(em, lb, st, en, tr, (int*)d_out);
}